// Round 14
// baseline (159.061 us; speedup 1.0000x reference)
//
#include <hip/hip_runtime.h>
#include <hip/hip_bf16.h>

#define N_NODES 100000
#define N_EDGES 1600000
#define DIM 64
#define NB 196                 // buckets of 512 nodes (t>>9)
#define CAP 9216               // slab capacity (mean 8163 + ~11 sigma; fixed input)
#define SMASK 0x1FFFFu         // 17 bits for source id
#define HALF_SRC 50000         // source split point (table half = 3.2 MB, L2-fits)
#define P1 391                 // partition blocks (K1)
#define T1 781                 // transform blocks in K1 (64 rows each) -> rows [0,49984)
#define R1 (T1 * 64)           // 49984
#define T2 196                 // transform blocks in K2 (256 rows each) -> rows [R1,100000)

typedef __attribute__((ext_vector_type(8))) short bf16x8;
typedef __attribute__((ext_vector_type(4))) float f32x4;
typedef __attribute__((ext_vector_type(2))) float f32x2;
typedef __attribute__((ext_vector_type(2))) unsigned int u32x2;

__device__ __forceinline__ unsigned short f2bs(float f) {
    __hip_bfloat16 h = __float2bfloat16(f);
    return *reinterpret_cast<unsigned short*>(&h);
}
__device__ __forceinline__ float bs2f(unsigned int u16) {
    return __uint_as_float(u16 << 16);
}
template <typename T>
__device__ __forceinline__ T ntload(const T* p) { return __builtin_nontemporal_load(p); }

// Shared transform tile body: 16 rows starting at r0 (one wave).
__device__ __forceinline__ void transform_tile(
    const float* __restrict__ x, const unsigned short* WB,
    const float* __restrict__ b_msg,
    unsigned int* __restrict__ Xs8, unsigned int* __restrict__ Xt8,
    int r0, int lane)
{
    f32x4 acc[8];
    #pragma unroll
    for (int ct = 0; ct < 8; ++ct) acc[ct] = (f32x4){0.f, 0.f, 0.f, 0.f};

    const int r = r0 + (lane & 15);
    #pragma unroll
    for (int kk = 0; kk < 2; ++kk) {
        const int off = kk * 32 + ((lane >> 4) << 3);
        const float4* xp = reinterpret_cast<const float4*>(&x[r * 64 + off]);
        const float4 p0 = xp[0], p1 = xp[1];
        bf16x8 a;
        a[0] = (short)f2bs(p0.x); a[1] = (short)f2bs(p0.y);
        a[2] = (short)f2bs(p0.z); a[3] = (short)f2bs(p0.w);
        a[4] = (short)f2bs(p1.x); a[5] = (short)f2bs(p1.y);
        a[6] = (short)f2bs(p1.z); a[7] = (short)f2bs(p1.w);
        #pragma unroll
        for (int ct = 0; ct < 8; ++ct) {
            const bf16x8 b = *reinterpret_cast<const bf16x8*>(
                &WB[(((ct << 1) | kk) * 64 + lane) << 3]);
            acc[ct] = __builtin_amdgcn_mfma_f32_16x16x32_bf16(a, b, acc[ct], 0, 0, 0);
        }
    }

    const int fr = lane & 15;
    const int rb = r0 + ((lane >> 4) << 2);
    const float bj0 = b_msg[fr],      bj1 = b_msg[16 + fr];
    const float bj2 = b_msg[32 + fr], bj3 = b_msg[48 + fr];
    #pragma unroll
    for (int q = 0; q < 4; ++q) {
        unsigned int xs = 0;
        xs = (unsigned)__builtin_amdgcn_cvt_pk_fp8_f32(acc[0][q], acc[1][q], (int)xs, false);
        xs = (unsigned)__builtin_amdgcn_cvt_pk_fp8_f32(acc[2][q], acc[3][q], (int)xs, true);
        Xs8[(rb + q) * 16 + fr] = xs;
        unsigned int xt = 0;
        xt = (unsigned)__builtin_amdgcn_cvt_pk_fp8_f32(acc[4][q] + bj0, acc[5][q] + bj1, (int)xt, false);
        xt = (unsigned)__builtin_amdgcn_cvt_pk_fp8_f32(acc[6][q] + bj2, acc[7][q] + bj3, (int)xt, true);
        Xt8[(rb + q) * 16 + fr] = xt;
    }
}

// K1 (3 roles, 256 thr): [0,P1) edge partition; [P1,P1+T1) transform rows
// [0,R1); last block precomputes W_upd fragments -> wfrag.
__global__ __launch_bounds__(256) void k1_part_xform(
    const float* __restrict__ x, const float* __restrict__ W_msg,
    const float* __restrict__ b_msg,
    unsigned int* __restrict__ Xs8, unsigned int* __restrict__ Xt8,
    const int* __restrict__ eidx, int* __restrict__ bcursor,
    unsigned int* __restrict__ pairs,
    const float* __restrict__ W_upd, unsigned short* __restrict__ wfrag)
{
    __shared__ __align__(16) char smem[35200];
    const int tid = threadIdx.x, lane = tid & 63, wid = tid >> 6;

    if (blockIdx.x >= P1 + T1) {
        for (int i = tid; i < 8192; i += 256) {
            const int j = i & 7, l = (i >> 3) & 63, kk = (i >> 9) & 3, ct = i >> 11;
            const int hi = l >> 4;
            int k;
            if (kk < 2) k = kk * 32 + (hi << 3) + j;
            else        k = 64 + ((j & 3) << 4) + ((kk - 2) << 3) + (hi << 1) + (j >> 2);
            const int c = ct * 16 + (l & 15);
            wfrag[i] = f2bs(W_upd[k * 64 + c]);
        }
    } else if (blockIdx.x >= P1) {
        unsigned short* WB = reinterpret_cast<unsigned short*>(smem);   // [8192]
        const int tb = blockIdx.x - P1;
        for (int i = tid; i < 8192; i += 256) {
            const int j = i & 7, l = (i >> 3) & 63, kk = (i >> 9) & 1, ct = i >> 10;
            const int k = kk * 32 + ((l >> 4) << 3) + j;
            const int c = ct * 16 + (l & 15);
            WB[i] = f2bs(W_msg[(((c >> 6) << 6) + k) * 64 + (c & 63)]);
        }
        __syncthreads();
        transform_tile(x, WB, b_msg, Xs8, Xt8, tb * 64 + wid * 16, lane);
    } else {
        unsigned int* sbuf = reinterpret_cast<unsigned int*>(smem);          // [4096]
        int* dbase = reinterpret_cast<int*>(smem + 16384);                   // [4096]
        int* tcnt  = reinterpret_cast<int*>(smem + 32768);                   // [NB]
        int* toff  = tcnt + NB;
        int* gpos  = toff + NB;
        int* wsum  = gpos + NB;                                              // [4]

        const int base = blockIdx.x * 4096;
        const int tcount = min(4096, N_EDGES - base);
        if (tid < NB) tcnt[tid] = 0;
        __syncthreads();

        unsigned int pk[16]; int bb[16]; int rk[16];
        #pragma unroll
        for (int j = 0; j < 16; ++j) {
            const int idx = base + j * 256 + tid;
            bb[j] = -1;
            if (idx < N_EDGES) {
                const int sv = eidx[idx];
                const int tv = eidx[N_EDGES + idx];
                bb[j] = tv >> 9;
                pk[j] = (unsigned)sv | ((unsigned)(tv & 511) << 17);
                rk[j] = atomicAdd(&tcnt[bb[j]], 1);
            }
        }
        __syncthreads();

        const int v = (tid < NB) ? tcnt[tid] : 0;
        int s = v;
        #pragma unroll
        for (int d = 1; d < 64; d <<= 1) { int u = __shfl_up(s, d); if (lane >= d) s += u; }
        if (lane == 63) wsum[wid] = s;
        __syncthreads();
        if (wid == 0) {
            int ws = (lane < 4) ? wsum[lane] : 0;
            #pragma unroll
            for (int d = 1; d < 4; d <<= 1) { int u = __shfl_up(ws, d); if (lane >= d) ws += u; }
            if (lane < 4) wsum[lane] = ws;
        }
        __syncthreads();
        const int exc = (wid ? wsum[wid - 1] : 0) + s - v;
        if (tid < NB) {
            toff[tid] = exc;
            gpos[tid] = tid * CAP + (v ? atomicAdd(&bcursor[tid], v) : 0);
        }
        __syncthreads();

        #pragma unroll
        for (int j = 0; j < 16; ++j) {
            if (bb[j] >= 0) {
                const int l = toff[bb[j]] + rk[j];
                sbuf[l]  = pk[j];
                dbase[l] = gpos[bb[j]] + rk[j];
            }
        }
        __syncthreads();
        for (int i = tid; i < tcount; i += 256)
            pairs[dbase[i]] = sbuf[i];
    }
}

// K2 (2 roles, 1024 thr): [0,NB) per-bucket TWO-LEVEL counting sort
// (key = local_node*2 + (s>=HALF_SRC)) -> csr + row/deg/mid;
// [NB,NB+T2): transform rows [R1, 100000).
__global__ __launch_bounds__(1024) void k2_sort_xform(
    const int* __restrict__ bcursor, const unsigned int* __restrict__ pairs,
    int* __restrict__ csr, int* __restrict__ deg, int* __restrict__ row,
    int* __restrict__ mid,
    const float* __restrict__ x, const float* __restrict__ W_msg,
    const float* __restrict__ b_msg,
    unsigned int* __restrict__ Xs8, unsigned int* __restrict__ Xt8)
{
    __shared__ __align__(16) char smem[63616];
    const int tid = threadIdx.x, lane = tid & 63, wid = tid >> 6;

    if (blockIdx.x >= NB) {
        unsigned short* WB = reinterpret_cast<unsigned short*>(smem);   // [8192]
        const int tb = blockIdx.x - NB;
        for (int i = tid; i < 8192; i += 1024) {
            const int j = i & 7, l = (i >> 3) & 63, kk = (i >> 9) & 1, ct = i >> 10;
            const int k = kk * 32 + ((l >> 4) << 3) + j;
            const int c = ct * 16 + (l & 15);
            WB[i] = f2bs(W_msg[(((c >> 6) << 6) + k) * 64 + (c & 63)]);
        }
        __syncthreads();
        const int r0 = R1 + tb * 256 + wid * 16;
        if (r0 >= N_NODES) return;                 // N%16==0, wave-uniform
        transform_tile(x, WB, b_msg, Xs8, Xt8, r0, lane);
    } else {
        unsigned int*   ebuf = reinterpret_cast<unsigned int*>(smem);           // [CAP]
        unsigned short* rbuf = reinterpret_cast<unsigned short*>(smem + 36864); // [CAP]
        int* ncnt = reinterpret_cast<int*>(smem + 55296);                       // [1024]
        int* noff = reinterpret_cast<int*>(smem + 59392);                       // [1024]
        int* wsum = reinterpret_cast<int*>(smem + 63488);                       // [16]

        const int b = blockIdx.x;
        const int s0 = b * CAP;
        const int cnt = bcursor[b];               // count (cursor started at 0)
        ncnt[tid] = 0;
        __syncthreads();

        for (int i = tid; i < cnt; i += 1024) {
            const unsigned int p = pairs[s0 + i];
            const int key = (int)((p >> 17) << 1) | ((p & SMASK) >= HALF_SRC ? 1 : 0);
            ebuf[i] = p;
            rbuf[i] = (unsigned short)atomicAdd(&ncnt[key], 1);
        }
        __syncthreads();

        const int v = ncnt[tid];
        int s = v;
        #pragma unroll
        for (int d = 1; d < 64; d <<= 1) { int u = __shfl_up(s, d); if (lane >= d) s += u; }
        if (lane == 63) wsum[wid] = s;
        __syncthreads();
        if (wid == 0) {
            int ws = (lane < 16) ? wsum[lane] : 0;
            #pragma unroll
            for (int d = 1; d < 16; d <<= 1) { int u = __shfl_up(ws, d); if (lane >= d) ws += u; }
            if (lane < 16) wsum[lane] = ws;
        }
        __syncthreads();
        const int exc = (wid ? wsum[wid - 1] : 0) + s - v;
        noff[tid] = exc;
        __syncthreads();

        if (tid < 512) {
            const int n = b * 512 + tid;
            if (n < N_NODES) {
                deg[n] = ncnt[2 * tid] + ncnt[2 * tid + 1];
                mid[n] = ncnt[2 * tid];
                row[n] = s0 + noff[2 * tid];
            }
        }
        for (int i = tid; i < cnt; i += 1024) {
            const unsigned int p = ebuf[i];
            const int key = (int)((p >> 17) << 1) | ((p & SMASK) >= HALF_SRC ? 1 : 0);
            csr[s0 + noff[key] + (int)rbuf[i]] = (int)(p & SMASK);
        }
    }
}

__device__ __forceinline__ void acc_fp8(unsigned int u,
    float t0, float t1, float t2, float t3,
    float& a0, float& a1, float& a2, float& a3)
{
    const f32x2 lo = __builtin_amdgcn_cvt_pk_f32_fp8(u, false);
    const f32x2 hi = __builtin_amdgcn_cvt_pk_f32_fp8(u, true);
    a0 += fmaxf(lo.x + t0, 0.f);
    a1 += fmaxf(lo.y + t1, 0.f);
    a2 += fmaxf(hi.x + t2, 0.f);
    a3 += fmaxf(hi.y + t3, 0.f);
}

// Deep-ILP gather over csr[start, start+cnt2): 8 loads in flight per quarter.
__device__ __forceinline__ void gather_range(
    const int* __restrict__ csr, const unsigned int* __restrict__ Xs8,
    int start, int cnt2, int c, int q,
    float t0, float t1, float t2, float t3,
    float& a0, float& a1, float& a2, float& a3)
{
    if (cnt2 <= 0) return;
    int i = 0;
    for (; i + 32 <= cnt2; i += 32) {
        int sv[8];
        #pragma unroll
        for (int k = 0; k < 8; ++k) sv[k] = ntload(&csr[start + i + 4 * k + q]);
        unsigned int u[8];
        #pragma unroll
        for (int k = 0; k < 8; ++k) u[k] = Xs8[sv[k] * 16 + c];
        #pragma unroll
        for (int k = 0; k < 8; ++k) acc_fp8(u[k], t0, t1, t2, t3, a0, a1, a2, a3);
    }
    const int rem = cnt2 - i;
    if (rem > 0) {
        const int lastIdx = start + cnt2 - 1;
        int sv[8]; bool vm[8];
        #pragma unroll
        for (int k = 0; k < 8; ++k) {
            const int e = i + 4 * k + q;
            vm[k] = (e < cnt2);
            sv[k] = ntload(&csr[vm[k] ? (start + e) : lastIdx]);
        }
        unsigned int u[8];
        #pragma unroll
        for (int k = 0; k < 8; ++k) u[k] = Xs8[sv[k] * 16 + c];
        #pragma unroll
        for (int k = 0; k < 8; ++k) {
            const f32x2 lo = __builtin_amdgcn_cvt_pk_f32_fp8(u[k], false);
            const f32x2 hi = __builtin_amdgcn_cvt_pk_f32_fp8(u[k], true);
            if (vm[k]) {
                a0 += fmaxf(lo.x + t0, 0.f);
                a1 += fmaxf(lo.y + t1, 0.f);
                a2 += fmaxf(hi.x + t2, 0.f);
                a3 += fmaxf(hi.y + t3, 0.f);
            }
        }
    }
}

// K3: source-half A (s < HALF_SRC). Wave per node; table half = 3.2 MB -> L2
// resident per XCD. Streams (csr/Xt8/row/mid) are nontemporal. Writes raw
// bf16 partial sums.
__global__ __launch_bounds__(256) void aggregate_half(
    const int* __restrict__ row, const int* __restrict__ mid,
    const int* __restrict__ csr,
    const unsigned int* __restrict__ Xs8, const unsigned int* __restrict__ Xt8,
    u32x2* __restrict__ aggP)
{
    const int n = blockIdx.x * 4 + (threadIdx.x >> 6);
    const int lane = threadIdx.x & 63;
    if (n >= N_NODES) return;
    const int c = lane & 15, q = lane >> 4;
    const int start = ntload(&row[n]);
    const int m = ntload(&mid[n]);
    const unsigned int tp = ntload(&Xt8[n * 16 + c]);
    const f32x2 tlo = __builtin_amdgcn_cvt_pk_f32_fp8(tp, false);
    const f32x2 thi = __builtin_amdgcn_cvt_pk_f32_fp8(tp, true);
    float a0 = 0.f, a1 = 0.f, a2 = 0.f, a3 = 0.f;

    gather_range(csr, Xs8, start, m, c, q, tlo.x, tlo.y, thi.x, thi.y, a0, a1, a2, a3);

    a0 += __shfl_xor(a0, 16); a0 += __shfl_xor(a0, 32);
    a1 += __shfl_xor(a1, 16); a1 += __shfl_xor(a1, 32);
    a2 += __shfl_xor(a2, 16); a2 += __shfl_xor(a2, 32);
    a3 += __shfl_xor(a3, 16); a3 += __shfl_xor(a3, 32);
    if (q == 0) {
        u32x2 v2;                                  // raw sums, bf16
        v2[0] = (unsigned)f2bs(a0) | ((unsigned)f2bs(a1) << 16);
        v2[1] = (unsigned)f2bs(a2) | ((unsigned)f2bs(a3) << 16);
        aggP[n * 16 + c] = v2;
    }
}

// K4 (fused half-B aggregate + update): 16-node block, 16 waves, node per wave.
// Gathers s >= HALF_SRC (table half B, L2-resident), adds A's partial, divides,
// then waves 0..3 run the MFMA update (x prefetched nontemporal).
__global__ __launch_bounds__(1024, 8) void agg_update(
    const int* __restrict__ row, const int* __restrict__ mid,
    const int* __restrict__ deg, const int* __restrict__ csr,
    const unsigned int* __restrict__ Xs8, const unsigned int* __restrict__ Xt8,
    const u32x2* __restrict__ aggP,
    const float* __restrict__ x, const unsigned short* __restrict__ wfrag,
    const float* __restrict__ b_upd, float* __restrict__ out)
{
    __shared__ unsigned short WB[8192];
    __shared__ uint2 aggT[16][18];        // 144B row stride: 2-way max bank alias

    const int tid = threadIdx.x, lane = tid & 63, w = tid >> 6;   // w = 0..15
    const int n0 = blockIdx.x * 16;
    const int fr = lane & 15, hi = lane >> 4;

    // prefetch phase-2 x operands + bias (waves 0..3; wave-uniform branch)
    f32x4 px0, px1, px2, px3; float bj = 0.f;
    if (w < 4) {
        const int r = n0 + fr;
        px0 = ntload(reinterpret_cast<const f32x4*>(&x[r * 64 + (hi << 3)]));
        px1 = ntload(reinterpret_cast<const f32x4*>(&x[r * 64 + (hi << 3) + 4]));
        px2 = ntload(reinterpret_cast<const f32x4*>(&x[r * 64 + 32 + (hi << 3)]));
        px3 = ntload(reinterpret_cast<const f32x4*>(&x[r * 64 + 32 + (hi << 3) + 4]));
        bj = b_upd[w * 16 + fr];
    }

    reinterpret_cast<bf16x8*>(WB)[tid] = reinterpret_cast<const bf16x8*>(wfrag)[tid];

    // ---- Phase 1: wave w aggregates node n0+w over half-B edges
    const int n = n0 + w;
    const int c = lane & 15, q = lane >> 4;
    const int start = ntload(&row[n]);
    const int m = ntload(&mid[n]);
    const int d = ntload(&deg[n]);
    const unsigned int tp = ntload(&Xt8[n * 16 + c]);
    const f32x2 tlo = __builtin_amdgcn_cvt_pk_f32_fp8(tp, false);
    const f32x2 thi = __builtin_amdgcn_cvt_pk_f32_fp8(tp, true);
    float a0 = 0.f, a1 = 0.f, a2 = 0.f, a3 = 0.f;

    gather_range(csr, Xs8, start + m, d - m, c, q, tlo.x, tlo.y, thi.x, thi.y,
                 a0, a1, a2, a3);

    a0 += __shfl_xor(a0, 16); a0 += __shfl_xor(a0, 32);
    a1 += __shfl_xor(a1, 16); a1 += __shfl_xor(a1, 32);
    a2 += __shfl_xor(a2, 16); a2 += __shfl_xor(a2, 32);
    a3 += __shfl_xor(a3, 16); a3 += __shfl_xor(a3, 32);
    if (q == 0) {
        const u32x2 par = ntload(&aggP[n * 16 + c]);   // A's partial (bf16 sums)
        a0 += bs2f(par[0] & 0xffffu);
        a1 += bs2f(par[0] >> 16);
        a2 += bs2f(par[1] & 0xffffu);
        a3 += bs2f(par[1] >> 16);
        const float inv = (d > 0) ? 1.0f / (float)d : 0.f;
        uint2 v2;
        v2.x = (unsigned)f2bs(a0 * inv) | ((unsigned)f2bs(a1 * inv) << 16);
        v2.y = (unsigned)f2bs(a2 * inv) | ((unsigned)f2bs(a3 * inv) << 16);
        aggT[w][c] = v2;
    }
    __syncthreads();

    // ---- Phase 2: waves 0..3 -> col-tile ct = w; one 16-row tile, K=128
    if (w < 4) {
        const int ct = w;
        f32x4 acc = (f32x4){0.f, 0.f, 0.f, 0.f};
        #pragma unroll
        for (int kk = 0; kk < 4; ++kk) {
            bf16x8 a;
            if (kk == 0) {
                a[0] = (short)f2bs(px0[0]); a[1] = (short)f2bs(px0[1]);
                a[2] = (short)f2bs(px0[2]); a[3] = (short)f2bs(px0[3]);
                a[4] = (short)f2bs(px1[0]); a[5] = (short)f2bs(px1[1]);
                a[6] = (short)f2bs(px1[2]); a[7] = (short)f2bs(px1[3]);
            } else if (kk == 1) {
                a[0] = (short)f2bs(px2[0]); a[1] = (short)f2bs(px2[1]);
                a[2] = (short)f2bs(px2[2]); a[3] = (short)f2bs(px2[3]);
                a[4] = (short)f2bs(px3[0]); a[5] = (short)f2bs(px3[1]);
                a[6] = (short)f2bs(px3[2]); a[7] = (short)f2bs(px3[3]);
            } else {
                a = *reinterpret_cast<const bf16x8*>(
                    &aggT[fr][((kk - 2) << 3) + (hi << 1)]);
            }
            const bf16x8 b = *reinterpret_cast<const bf16x8*>(
                &WB[(((ct << 2) | kk) * 64 + lane) << 3]);
            acc = __builtin_amdgcn_mfma_f32_16x16x32_bf16(a, b, acc, 0, 0, 0);
        }
        const int rb = n0 + (hi << 2);
        const int cc = ct * 16 + fr;
        #pragma unroll
        for (int qq = 0; qq < 4; ++qq)
            out[(rb + qq) * 64 + cc] = fmaxf(acc[qq] + bj, 0.f);
    }
}

extern "C" void kernel_launch(void* const* d_in, const int* in_sizes, int n_in,
                              void* d_out, int out_size, void* d_ws, size_t ws_size,
                              hipStream_t stream) {
    const float* x     = (const float*)d_in[0];
    const int*   eidx  = (const int*)  d_in[1];   // [2][E] int32
    const float* W_msg = (const float*)d_in[2];
    const float* b_msg = (const float*)d_in[3];
    const float* W_upd = (const float*)d_in[4];
    const float* b_upd = (const float*)d_in[5];
    float* out = (float*)d_out;

    int* deg     = (int*)d_ws;                         // [N]
    int* row     = deg + N_NODES;                      // [N]
    int* mid     = row + N_NODES;                      // [N]
    int* bcursor = mid + N_NODES;                      // [256 pad]
    unsigned short* wfrag = (unsigned short*)(bcursor + 256);   // [8192] 16KB
    unsigned int* pairs = (unsigned int*)(wfrag + 8192);        // [NB*CAP] 7.2 MB
    int* csr     = (int*)(pairs + NB * CAP);                    // [NB*CAP] 7.2 MB
    unsigned int* Xs8 = (unsigned int*)(csr + NB * CAP);        // [N][16] fp8 6.4 MB
    unsigned int* Xt8 = Xs8 + (size_t)N_NODES * 16;             // [N][16] fp8 6.4 MB
    u32x2* aggP  = (u32x2*)(Xt8 + (size_t)N_NODES * 16);        // [N][16] bf16 12.8 MB

    hipMemsetAsync(bcursor, 0, NB * sizeof(int), stream);
    k1_part_xform<<<P1 + T1 + 1, 256, 0, stream>>>(
        x, W_msg, b_msg, Xs8, Xt8, eidx, bcursor, pairs, W_upd, wfrag);
    k2_sort_xform<<<NB + T2, 1024, 0, stream>>>(
        bcursor, pairs, csr, deg, row, mid, x, W_msg, b_msg, Xs8, Xt8);
    aggregate_half<<<(N_NODES + 3) / 4, 256, 0, stream>>>(
        row, mid, csr, Xs8, Xt8, aggP);
    agg_update<<<N_NODES / 16, 1024, 0, stream>>>(
        row, mid, deg, csr, Xs8, Xt8, aggP, x, wfrag, b_upd, out);
}

// Round 15
// 101.661 us; speedup vs baseline: 1.5646x; 1.5646x over previous
//
#include <hip/hip_runtime.h>
#include <hip/hip_bf16.h>

#define N_NODES 100000
#define N_EDGES 1600000
#define DIM 64
#define NB 196                 // buckets of 512 nodes (t>>9)
#define CAP 9216               // slab capacity (mean 8163 + ~11 sigma; fixed input)
#define SMASK 0x1FFFFu         // 17 bits for source id
#define P1 391                 // partition blocks (K1)
#define T1 781                 // transform blocks in K1 (64 rows each) -> rows [0,49984)
#define R1 (T1 * 64)           // 49984
#define T2 196                 // transform blocks in K2 (256 rows each) -> rows [R1,100000)

typedef __attribute__((ext_vector_type(8))) short bf16x8;
typedef __attribute__((ext_vector_type(4))) float f32x4;
typedef __attribute__((ext_vector_type(2))) float f32x2;

__device__ __forceinline__ unsigned short f2bs(float f) {
    __hip_bfloat16 h = __float2bfloat16(f);
    return *reinterpret_cast<unsigned short*>(&h);
}

// Shared transform tile body: 16 rows starting at r0 (one wave).
// Xs8 = fp8(x@Wm[0:64]), Xt8 = fp8(x@Wm[64:128]+b), permuted uint layout.
__device__ __forceinline__ void transform_tile(
    const float* __restrict__ x, const unsigned short* WB,
    const float* __restrict__ b_msg,
    unsigned int* __restrict__ Xs8, unsigned int* __restrict__ Xt8,
    int r0, int lane)
{
    f32x4 acc[8];
    #pragma unroll
    for (int ct = 0; ct < 8; ++ct) acc[ct] = (f32x4){0.f, 0.f, 0.f, 0.f};

    const int r = r0 + (lane & 15);
    #pragma unroll
    for (int kk = 0; kk < 2; ++kk) {
        const int off = kk * 32 + ((lane >> 4) << 3);
        const float4* xp = reinterpret_cast<const float4*>(&x[r * 64 + off]);
        const float4 p0 = xp[0], p1 = xp[1];
        bf16x8 a;
        a[0] = (short)f2bs(p0.x); a[1] = (short)f2bs(p0.y);
        a[2] = (short)f2bs(p0.z); a[3] = (short)f2bs(p0.w);
        a[4] = (short)f2bs(p1.x); a[5] = (short)f2bs(p1.y);
        a[6] = (short)f2bs(p1.z); a[7] = (short)f2bs(p1.w);
        #pragma unroll
        for (int ct = 0; ct < 8; ++ct) {
            const bf16x8 b = *reinterpret_cast<const bf16x8*>(
                &WB[(((ct << 1) | kk) * 64 + lane) << 3]);
            acc[ct] = __builtin_amdgcn_mfma_f32_16x16x32_bf16(a, b, acc[ct], 0, 0, 0);
        }
    }

    // C/D: col = ct*16 + (lane&15), row = rb + q  [m89-verified]
    const int fr = lane & 15;
    const int rb = r0 + ((lane >> 4) << 2);
    const float bj0 = b_msg[fr],      bj1 = b_msg[16 + fr];
    const float bj2 = b_msg[32 + fr], bj3 = b_msg[48 + fr];
    #pragma unroll
    for (int q = 0; q < 4; ++q) {
        unsigned int xs = 0;
        xs = (unsigned)__builtin_amdgcn_cvt_pk_fp8_f32(acc[0][q], acc[1][q], (int)xs, false);
        xs = (unsigned)__builtin_amdgcn_cvt_pk_fp8_f32(acc[2][q], acc[3][q], (int)xs, true);
        Xs8[(rb + q) * 16 + fr] = xs;
        unsigned int xt = 0;
        xt = (unsigned)__builtin_amdgcn_cvt_pk_fp8_f32(acc[4][q] + bj0, acc[5][q] + bj1, (int)xt, false);
        xt = (unsigned)__builtin_amdgcn_cvt_pk_fp8_f32(acc[6][q] + bj2, acc[7][q] + bj3, (int)xt, true);
        Xt8[(rb + q) * 16 + fr] = xt;
    }
}

// K1 (3 roles, 256 thr): [0,P1) edge partition; [P1,P1+T1) transform rows
// [0,R1); last block precomputes W_upd fragments -> wfrag.
__global__ __launch_bounds__(256) void k1_part_xform(
    const float* __restrict__ x, const float* __restrict__ W_msg,
    const float* __restrict__ b_msg,
    unsigned int* __restrict__ Xs8, unsigned int* __restrict__ Xt8,
    const int* __restrict__ eidx, int* __restrict__ bcursor,
    unsigned int* __restrict__ pairs,
    const float* __restrict__ W_upd, unsigned short* __restrict__ wfrag)
{
    __shared__ __align__(16) char smem[35200];
    const int tid = threadIdx.x, lane = tid & 63, wid = tid >> 6;

    if (blockIdx.x >= P1 + T1) {
        // ---- wfrag role: W_upd -> MFMA B-fragment layout (bf16), once.
        for (int i = tid; i < 8192; i += 256) {
            const int j = i & 7, l = (i >> 3) & 63, kk = (i >> 9) & 3, ct = i >> 11;
            const int hi = l >> 4;
            int k;
            if (kk < 2) k = kk * 32 + (hi << 3) + j;
            else        k = 64 + ((j & 3) << 4) + ((kk - 2) << 3) + (hi << 1) + (j >> 2);
            const int c = ct * 16 + (l & 15);
            wfrag[i] = f2bs(W_upd[k * 64 + c]);
        }
    } else if (blockIdx.x >= P1) {
        // ---- transform role (rows [0, R1))
        unsigned short* WB = reinterpret_cast<unsigned short*>(smem);   // [8192]
        const int tb = blockIdx.x - P1;
        for (int i = tid; i < 8192; i += 256) {
            const int j = i & 7, l = (i >> 3) & 63, kk = (i >> 9) & 1, ct = i >> 10;
            const int k = kk * 32 + ((l >> 4) << 3) + j;
            const int c = ct * 16 + (l & 15);
            WB[i] = f2bs(W_msg[(((c >> 6) << 6) + k) * 64 + (c & 63)]);
        }
        __syncthreads();
        transform_tile(x, WB, b_msg, Xs8, Xt8, tb * 64 + wid * 16, lane);
    } else {
        // ---- partition role: LDS-staged scatter of packed edges into slabs.
        unsigned int* sbuf = reinterpret_cast<unsigned int*>(smem);          // [4096]
        int* dbase = reinterpret_cast<int*>(smem + 16384);                   // [4096]
        int* tcnt  = reinterpret_cast<int*>(smem + 32768);                   // [NB]
        int* toff  = tcnt + NB;
        int* gpos  = toff + NB;
        int* wsum  = gpos + NB;                                              // [4]

        const int base = blockIdx.x * 4096;
        const int tcount = min(4096, N_EDGES - base);
        if (tid < NB) tcnt[tid] = 0;
        __syncthreads();

        unsigned int pk[16]; int bb[16]; int rk[16];
        #pragma unroll
        for (int j = 0; j < 16; ++j) {
            const int idx = base + j * 256 + tid;
            bb[j] = -1;
            if (idx < N_EDGES) {
                const int sv = eidx[idx];
                const int tv = eidx[N_EDGES + idx];
                bb[j] = tv >> 9;
                pk[j] = (unsigned)sv | ((unsigned)(tv & 511) << 17);
                rk[j] = atomicAdd(&tcnt[bb[j]], 1);
            }
        }
        __syncthreads();

        const int v = (tid < NB) ? tcnt[tid] : 0;
        int s = v;
        #pragma unroll
        for (int d = 1; d < 64; d <<= 1) { int u = __shfl_up(s, d); if (lane >= d) s += u; }
        if (lane == 63) wsum[wid] = s;
        __syncthreads();
        if (wid == 0) {
            int ws = (lane < 4) ? wsum[lane] : 0;
            #pragma unroll
            for (int d = 1; d < 4; d <<= 1) { int u = __shfl_up(ws, d); if (lane >= d) ws += u; }
            if (lane < 4) wsum[lane] = ws;
        }
        __syncthreads();
        const int exc = (wid ? wsum[wid - 1] : 0) + s - v;
        if (tid < NB) {
            toff[tid] = exc;
            gpos[tid] = tid * CAP + (v ? atomicAdd(&bcursor[tid], v) : 0);
        }
        __syncthreads();

        #pragma unroll
        for (int j = 0; j < 16; ++j) {
            if (bb[j] >= 0) {
                const int l = toff[bb[j]] + rk[j];
                sbuf[l]  = pk[j];
                dbase[l] = gpos[bb[j]] + rk[j];
            }
        }
        __syncthreads();
        for (int i = tid; i < tcount; i += 256)
            pairs[dbase[i]] = sbuf[i];
    }
}

// K2 (2 roles, 1024 thr): [0,NB) per-bucket counting sort; [NB, NB+T2)
// transform rows [R1, 100000) (256 rows per block, 16 waves x 16-row tiles).
// Sort depends on K1's partition (stream order); transform is independent and
// overlaps the sort's LDS-atomic phases on other CUs.
__global__ __launch_bounds__(1024) void k2_sort_xform(
    const int* __restrict__ bcursor, const unsigned int* __restrict__ pairs,
    int* __restrict__ csr, int* __restrict__ deg, int* __restrict__ row,
    const float* __restrict__ x, const float* __restrict__ W_msg,
    const float* __restrict__ b_msg,
    unsigned int* __restrict__ Xs8, unsigned int* __restrict__ Xt8)
{
    __shared__ __align__(16) char smem[59424];
    const int tid = threadIdx.x, lane = tid & 63, wid = tid >> 6;

    if (blockIdx.x >= NB) {
        // ---- transform role (rows [R1, N))
        unsigned short* WB = reinterpret_cast<unsigned short*>(smem);   // [8192]
        const int tb = blockIdx.x - NB;
        for (int i = tid; i < 8192; i += 1024) {
            const int j = i & 7, l = (i >> 3) & 63, kk = (i >> 9) & 1, ct = i >> 10;
            const int k = kk * 32 + ((l >> 4) << 3) + j;
            const int c = ct * 16 + (l & 15);
            WB[i] = f2bs(W_msg[(((c >> 6) << 6) + k) * 64 + (c & 63)]);
        }
        __syncthreads();
        const int r0 = R1 + tb * 256 + wid * 16;
        if (r0 >= N_NODES) return;                 // N%16==0, wave-uniform
        transform_tile(x, WB, b_msg, Xs8, Xt8, r0, lane);
    } else {
        // ---- sort role: per-bucket counting sort in LDS -> csr + row/deg
        unsigned int*   ebuf = reinterpret_cast<unsigned int*>(smem);        // [CAP]
        unsigned short* rbuf = reinterpret_cast<unsigned short*>(smem + 36864); // [CAP]
        int* ncnt = reinterpret_cast<int*>(smem + 55296);                    // [512]
        int* noff = reinterpret_cast<int*>(smem + 57344);                    // [512]
        int* wsum = reinterpret_cast<int*>(smem + 59392);                    // [8]

        const int b = blockIdx.x;
        const int s0 = b * CAP;
        const int cnt = bcursor[b];               // count (cursor started at 0)
        if (tid < 512) ncnt[tid] = 0;
        __syncthreads();

        for (int i = tid; i < cnt; i += 1024) {
            const unsigned int p = pairs[s0 + i];
            ebuf[i] = p;
            rbuf[i] = (unsigned short)atomicAdd(&ncnt[p >> 17], 1);
        }
        __syncthreads();

        int v = 0, s = 0;
        if (tid < 512) {
            v = ncnt[tid];
            s = v;
            #pragma unroll
            for (int d = 1; d < 64; d <<= 1) { int u = __shfl_up(s, d); if (lane >= d) s += u; }
            if (lane == 63) wsum[wid] = s;
        }
        __syncthreads();
        if (wid == 0) {
            int ws = (lane < 8) ? wsum[lane] : 0;
            #pragma unroll
            for (int d = 1; d < 8; d <<= 1) { int u = __shfl_up(ws, d); if (lane >= d) ws += u; }
            if (lane < 8) wsum[lane] = ws;
        }
        __syncthreads();
        if (tid < 512) {
            const int exc = (wid ? wsum[wid - 1] : 0) + s - v;
            noff[tid] = exc;
            const int n = b * 512 + tid;
            if (n < N_NODES) { deg[n] = v; row[n] = s0 + exc; }
        }
        __syncthreads();

        for (int i = tid; i < cnt; i += 1024) {
            const unsigned int p = ebuf[i];
            csr[s0 + noff[p >> 17] + (int)rbuf[i]] = (int)(p & SMASK);
        }
    }
}

__device__ __forceinline__ void acc_fp8(unsigned int u,
    float t0, float t1, float t2, float t3,
    float& a0, float& a1, float& a2, float& a3)
{
    const f32x2 lo = __builtin_amdgcn_cvt_pk_f32_fp8(u, false);
    const f32x2 hi = __builtin_amdgcn_cvt_pk_f32_fp8(u, true);
    a0 += fmaxf(lo.x + t0, 0.f);
    a1 += fmaxf(lo.y + t1, 0.f);
    a2 += fmaxf(hi.x + t2, 0.f);
    a3 += fmaxf(hi.y + t3, 0.f);
}

// K3 (fused aggregate + update): 16-node block, 16 waves, one node per wave.
// x fragments for phase 2 are PREFETCHED into registers at kernel entry
// (waves 0..3) so the post-barrier critical path is LDS + MFMA + store only.
__global__ __launch_bounds__(1024, 8) void agg_update(
    const int* __restrict__ row, const int* __restrict__ deg,
    const int* __restrict__ csr,
    const unsigned int* __restrict__ Xs8, const unsigned int* __restrict__ Xt8,
    const float* __restrict__ x, const unsigned short* __restrict__ wfrag,
    const float* __restrict__ b_upd, float* __restrict__ out)
{
    __shared__ unsigned short WB[8192];   // staged W_upd fragments
    __shared__ uint2 aggT[16][18];        // 144B row stride: 2-way max bank alias

    const int tid = threadIdx.x, lane = tid & 63, w = tid >> 6;   // w = 0..15
    const int n0 = blockIdx.x * 16;
    const int fr = lane & 15, hi = lane >> 4;

    // prefetch phase-2 x operands + bias (waves 0..3 only; wave-uniform branch)
    float4 px0, px1, px2, px3; float bj = 0.f;
    if (w < 4) {
        const int r = n0 + fr;
        const float4* xp = reinterpret_cast<const float4*>(&x[r * 64 + (hi << 3)]);
        px0 = xp[0]; px1 = xp[1];                                  // kk=0
        const float4* xq = reinterpret_cast<const float4*>(&x[r * 64 + 32 + (hi << 3)]);
        px2 = xq[0]; px3 = xq[1];                                  // kk=1
        bj = b_upd[w * 16 + fr];
    }

    // stage W fragments: one b128 per thread (1024 x 16B = 16KB exactly)
    reinterpret_cast<bf16x8*>(WB)[tid] = reinterpret_cast<const bf16x8*>(wfrag)[tid];

    // ---- Phase 1: wave w aggregates node n0+w (deep-ILP gather)
    const int n = n0 + w;                 // always < N_NODES (100000 = 6250*16)
    const int c = lane & 15, q = lane >> 4;
    const int start = row[n], d = deg[n];
    const unsigned int tp = Xt8[n * 16 + c];
    const f32x2 tlo = __builtin_amdgcn_cvt_pk_f32_fp8(tp, false);
    const f32x2 thi = __builtin_amdgcn_cvt_pk_f32_fp8(tp, true);
    const float t0 = tlo.x, t1 = tlo.y, t2 = thi.x, t3 = thi.y;
    float a0 = 0.f, a1 = 0.f, a2 = 0.f, a3 = 0.f;

    if (d > 0) {
        int i = 0;
        for (; i + 32 <= d; i += 32) {            // rare (P(d>32) ~ 1e-4)
            int sv[8];
            #pragma unroll
            for (int k = 0; k < 8; ++k) sv[k] = csr[start + i + 4 * k + q];
            unsigned int u[8];
            #pragma unroll
            for (int k = 0; k < 8; ++k) u[k] = Xs8[sv[k] * 16 + c];
            #pragma unroll
            for (int k = 0; k < 8; ++k) acc_fp8(u[k], t0, t1, t2, t3, a0, a1, a2, a3);
        }
        const int rem = d - i;                    // 1..32 (or 0)
        if (rem > 0) {
            const int lastIdx = start + d - 1;
            int sv[8]; bool vm[8];
            #pragma unroll
            for (int k = 0; k < 8; ++k) {
                const int e = i + 4 * k + q;
                vm[k] = (e < d);
                sv[k] = csr[vm[k] ? (start + e) : lastIdx];
            }
            unsigned int u[8];
            #pragma unroll
            for (int k = 0; k < 8; ++k) u[k] = Xs8[sv[k] * 16 + c];
            #pragma unroll
            for (int k = 0; k < 8; ++k) {
                const f32x2 lo = __builtin_amdgcn_cvt_pk_f32_fp8(u[k], false);
                const f32x2 hi2 = __builtin_amdgcn_cvt_pk_f32_fp8(u[k], true);
                if (vm[k]) {
                    a0 += fmaxf(lo.x + t0, 0.f);
                    a1 += fmaxf(lo.y + t1, 0.f);
                    a2 += fmaxf(hi2.x + t2, 0.f);
                    a3 += fmaxf(hi2.y + t3, 0.f);
                }
            }
        }
    }

    a0 += __shfl_xor(a0, 16); a0 += __shfl_xor(a0, 32);
    a1 += __shfl_xor(a1, 16); a1 += __shfl_xor(a1, 32);
    a2 += __shfl_xor(a2, 16); a2 += __shfl_xor(a2, 32);
    a3 += __shfl_xor(a3, 16); a3 += __shfl_xor(a3, 32);
    if (q == 0) {
        const float inv = (d > 0) ? 1.0f / (float)d : 0.f;
        uint2 v2;                                  // f32 -> bf16 direct
        v2.x = (unsigned)f2bs(a0 * inv) | ((unsigned)f2bs(a1 * inv) << 16);
        v2.y = (unsigned)f2bs(a2 * inv) | ((unsigned)f2bs(a3 * inv) << 16);
        aggT[w][c] = v2;
    }
    __syncthreads();

    // ---- Phase 2: waves 0..3 -> col-tile ct = w; one 16-row tile, K=128
    if (w < 4) {
        const int ct = w;
        f32x4 acc = (f32x4){0.f, 0.f, 0.f, 0.f};
        #pragma unroll
        for (int kk = 0; kk < 4; ++kk) {
            bf16x8 a;
            if (kk == 0) {
                a[0] = (short)f2bs(px0.x); a[1] = (short)f2bs(px0.y);
                a[2] = (short)f2bs(px0.z); a[3] = (short)f2bs(px0.w);
                a[4] = (short)f2bs(px1.x); a[5] = (short)f2bs(px1.y);
                a[6] = (short)f2bs(px1.z); a[7] = (short)f2bs(px1.w);
            } else if (kk == 1) {
                a[0] = (short)f2bs(px2.x); a[1] = (short)f2bs(px2.y);
                a[2] = (short)f2bs(px2.z); a[3] = (short)f2bs(px2.w);
                a[4] = (short)f2bs(px3.x); a[5] = (short)f2bs(px3.y);
                a[6] = (short)f2bs(px3.z); a[7] = (short)f2bs(px3.w);
            } else {
                a = *reinterpret_cast<const bf16x8*>(
                    &aggT[fr][((kk - 2) << 3) + (hi << 1)]);
            }
            const bf16x8 b = *reinterpret_cast<const bf16x8*>(
                &WB[(((ct << 2) | kk) * 64 + lane) << 3]);
            acc = __builtin_amdgcn_mfma_f32_16x16x32_bf16(a, b, acc, 0, 0, 0);
        }
        const int rb = n0 + (hi << 2);
        const int cc = ct * 16 + fr;
        #pragma unroll
        for (int qq = 0; qq < 4; ++qq)
            out[(rb + qq) * 64 + cc] = fmaxf(acc[qq] + bj, 0.f);
    }
}

extern "C" void kernel_launch(void* const* d_in, const int* in_sizes, int n_in,
                              void* d_out, int out_size, void* d_ws, size_t ws_size,
                              hipStream_t stream) {
    const float* x     = (const float*)d_in[0];
    const int*   eidx  = (const int*)  d_in[1];   // [2][E] int32
    const float* W_msg = (const float*)d_in[2];
    const float* b_msg = (const float*)d_in[3];
    const float* W_upd = (const float*)d_in[4];
    const float* b_upd = (const float*)d_in[5];
    float* out = (float*)d_out;

    int* deg     = (int*)d_ws;                         // [N]
    int* row     = deg + N_NODES;                      // [N]
    int* bcursor = row + N_NODES;                      // [256 pad]
    unsigned short* wfrag = (unsigned short*)(bcursor + 256);   // [8192] 16KB
    unsigned int* pairs = (unsigned int*)(wfrag + 8192);        // [NB*CAP] 7.2 MB
    int* csr     = (int*)(pairs + NB * CAP);                    // [NB*CAP] 7.2 MB
    unsigned int* Xs8 = (unsigned int*)(csr + NB * CAP);        // [N][16] fp8 6.4 MB
    unsigned int* Xt8 = Xs8 + (size_t)N_NODES * 16;             // [N][16] fp8 6.4 MB

    hipMemsetAsync(bcursor, 0, NB * sizeof(int), stream);
    k1_part_xform<<<P1 + T1 + 1, 256, 0, stream>>>(
        x, W_msg, b_msg, Xs8, Xt8, eidx, bcursor, pairs, W_upd, wfrag);
    k2_sort_xform<<<NB + T2, 1024, 0, stream>>>(
        bcursor, pairs, csr, deg, row, x, W_msg, b_msg, Xs8, Xt8);
    agg_update<<<N_NODES / 16, 1024, 0, stream>>>(row, deg, csr, Xs8, Xt8,
                                                  x, wfrag, b_upd, out);
}